// Round 1
// baseline (406.019 us; speedup 1.0000x reference)
//
#include <hip/hip_runtime.h>

#define HDIM 64
#define BLK  256

// tanh(x) = 1 - 2/(exp(2x)+1); exp(2x) = 2^(x * 2*log2(e)).
// v_exp_f32 / v_rcp_f32 are ~1 ulp -> abs error ~1e-7, saturates correctly at +-inf.
__device__ __forceinline__ float tanh_fast(float v) {
    float e = __builtin_amdgcn_exp2f(v * 2.8853900817779268f);
    float r = __builtin_amdgcn_rcpf(e + 1.0f);
    return fmaf(-2.0f, r, 1.0f);
}

// One thread = one point. Per (h,k) inner iteration: 1 wave-uniform ds_read_b128
// (broadcast, conflict-free) + 4 v_fma_f32. CT folds W2[h,k]*W1[k,d] once per block.
__global__ __launch_bounds__(BLK) void curl_kernel(
    const float* __restrict__ x,  const float* __restrict__ W1,
    const float* __restrict__ b1, const float* __restrict__ W2,
    const float* __restrict__ b2, const float* __restrict__ W3,
    float* __restrict__ out, int npts)
{
    // 64 KiB exactly: {W2[h][k], W2[h][k]*W1[k][0], *W1[k][1], *W1[k][2]}
    __shared__ float4 sCT[HDIM * HDIM];

    const int t = threadIdx.x;
    for (int idx = t; idx < HDIM * HDIM; idx += BLK) {
        const int k = idx & (HDIM - 1);
        const float w2 = W2[idx];
        sCT[idx] = make_float4(w2, w2 * W1[k * 3 + 0],
                                   w2 * W1[k * 3 + 1],
                                   w2 * W1[k * 3 + 2]);
    }
    __syncthreads();

    const int n = blockIdx.x * BLK + t;
    if (n >= npts) return;

    const float x0 = x[n * 3 + 0];
    const float x1 = x[n * 3 + 1];
    const float x2 = x[n * 3 + 2];

    // Layer 1: h1 = tanh(W1 x + b1); D1 = 1 - h1^2. Both stay in VGPRs
    // (static indices after full unroll).
    float h1a[HDIM], d1a[HDIM];
#pragma unroll
    for (int i = 0; i < HDIM; ++i) {
        float a = fmaf(W1[i * 3 + 0], x0, b1[i]);
        a = fmaf(W1[i * 3 + 1], x1, a);
        a = fmaf(W1[i * 3 + 2], x2, a);
        const float th = tanh_fast(a);
        h1a[i] = th;
        d1a[i] = fmaf(-th, th, 1.0f);
    }

    // Layer 2 + Jacobian + curl, fused over h.
    // s0    = b2[h] + sum_k W2[h,k] * h1[k]          (h2 preactivation)
    // u_d   = sum_k  D1[k] * (W2[h,k]*W1[k,d])       (W2 @ T1 row)
    // curl += eps contraction of W3[:,h] * D2[h] * u
    float c0 = 0.f, c1 = 0.f, c2 = 0.f;
    float hb  = b2[0];
    float w30 = W3[0 * HDIM + 0];
    float w31 = W3[1 * HDIM + 0];
    float w32 = W3[2 * HDIM + 0];
#pragma unroll 1
    for (int h = 0; h < HDIM; ++h) {
        // Software-pipeline next row's epilogue constants under the k-loop.
        float hb_n = 0.f, w30_n = 0.f, w31_n = 0.f, w32_n = 0.f;
        if (h + 1 < HDIM) {
            hb_n  = b2[h + 1];
            w30_n = W3[0 * HDIM + h + 1];
            w31_n = W3[1 * HDIM + h + 1];
            w32_n = W3[2 * HDIM + h + 1];
        }

        float s0 = hb, u0 = 0.f, u1 = 0.f, u2 = 0.f;
        const float4* __restrict__ row = &sCT[h * HDIM];
#pragma unroll
        for (int k = 0; k < HDIM; ++k) {
            const float4 cw = row[k];
            s0 = fmaf(cw.x, h1a[k], s0);
            u0 = fmaf(cw.y, d1a[k], u0);
            u1 = fmaf(cw.z, d1a[k], u1);
            u2 = fmaf(cw.w, d1a[k], u2);
        }

        const float th = tanh_fast(s0);
        const float d2 = fmaf(-th, th, 1.0f);
        const float e0 = w30 * d2;
        const float e1 = w31 * d2;
        const float e2 = w32 * d2;
        // curl0 += J21 - J12 ; curl1 += J02 - J20 ; curl2 += J10 - J01
        c0 = fmaf(e2, u1, c0); c0 = fmaf(-e1, u2, c0);
        c1 = fmaf(e0, u2, c1); c1 = fmaf(-e2, u0, c1);
        c2 = fmaf(e1, u0, c2); c2 = fmaf(-e0, u1, c2);

        hb = hb_n; w30 = w30_n; w31 = w31_n; w32 = w32_n;
    }

    out[n * 3 + 0] = c0;
    out[n * 3 + 1] = c1;
    out[n * 3 + 2] = c2;
}

extern "C" void kernel_launch(void* const* d_in, const int* in_sizes, int n_in,
                              void* d_out, int out_size, void* d_ws, size_t ws_size,
                              hipStream_t stream) {
    const float* x  = (const float*)d_in[0];
    const float* W1 = (const float*)d_in[1];
    const float* b1 = (const float*)d_in[2];
    const float* W2 = (const float*)d_in[3];
    const float* b2 = (const float*)d_in[4];
    const float* W3 = (const float*)d_in[5];
    // d_in[6] (b3) is unused: it cancels in the Jacobian.
    float* out = (float*)d_out;

    const int npts = in_sizes[0] / 3;
    const int grid = (npts + BLK - 1) / BLK;
    hipLaunchKernelGGL(curl_kernel, dim3(grid), dim3(BLK), 0, stream,
                       x, W1, b1, W2, b2, W3, out, npts);
}